// Round 1
// baseline (507.059 us; speedup 1.0000x reference)
//
#include <hip/hip_runtime.h>

#define NN 10000
#define NEDGE 160000
#define NBATCH 64

// ---------------- workspace layout (units: floats) ----------------
// total ~72.6 MB
static constexpr size_t OFF_POS   = 0;                     // N*3
static constexpr size_t OFF_H     = 30016;                 // N*64
static constexpr size_t OFF_NF0   = OFF_H   + 640000;      // N*64
static constexpr size_t OFF_NUP   = OFF_NF0 + 640000;      // N*64
static constexpr size_t OFF_V3    = OFF_NUP + 640000;      // N*192
static constexpr size_t OFF_Q1    = OFF_V3  + 1920000;     // N*64
static constexpr size_t OFF_AGG   = OFF_Q1  + 640000;      // N*256 (float4[N*64])
static constexpr size_t OFF_WW    = OFF_AGG + 2560000;     // E*64
static constexpr size_t OFF_WY    = OFF_WW  + 10240000;    // E*4 (float4[E])
static constexpr size_t OFF_ESLOT = OFF_WY  + 640000;      // E ints
static constexpr size_t OFF_CSR   = OFF_ESLOT + 160000;    // N+1 ints (pad 10016)
static constexpr size_t OFF_CNT   = OFF_CSR + 10016;       // N ints
static constexpr size_t OFF_CUR   = OFF_CNT + 10016;       // N ints
static constexpr size_t OFF_BACC  = OFF_CUR + 10016;       // B*4 floats
static constexpr size_t WS_END    = OFF_BACC + 256;

__device__ __forceinline__ float silu_f(float x) {
  return x / (1.0f + __expf(-x));
}

// ---------------- setup ----------------
// h = [node_attrs/4, t[batch]] @ W_emb + b_emb ; nf0 = h ; pos_cur = positions
__global__ __launch_bounds__(256) void k_embed(
    const float* __restrict__ pos_in, const float* __restrict__ na,
    const float* __restrict__ t, const int* __restrict__ batch,
    const float* __restrict__ Wemb, const float* __restrict__ bemb,
    float* __restrict__ h, float* __restrict__ nf0, float* __restrict__ pos_cur) {
  int tid = blockIdx.x * 256 + threadIdx.x;   // exactly N*64 threads
  int n = tid >> 6, k = tid & 63;
  float acc = bemb[k];
  const float* arow = na + n * 10;
#pragma unroll
  for (int j = 0; j < 10; ++j)
    acc = fmaf(arow[j] * 0.25f, Wemb[j * 64 + k], acc);
  acc = fmaf(t[batch[n]], Wemb[10 * 64 + k], acc);
  h[tid] = acc;
  nf0[tid] = acc;
  if (k < 3) pos_cur[n * 3 + k] = pos_in[n * 3 + k];
}

__global__ __launch_bounds__(256) void k_count(const int* __restrict__ ei,
                                               int* __restrict__ counts) {
  int e = blockIdx.x * 256 + threadIdx.x;     // exactly E threads
  atomicAdd(&counts[ei[NEDGE + e]], 1);
}

// single-block exclusive scan over counts -> csroff (N+1)
__global__ __launch_bounds__(1024) void k_scan(const int* __restrict__ counts,
                                               int* __restrict__ offs) {
  __shared__ int lds[1024];
  __shared__ int carry_s;
  int tid = threadIdx.x;
  if (tid == 0) carry_s = 0;
  __syncthreads();
  for (int base = 0; base < NN; base += 1024) {
    int idx = base + tid;
    int v = (idx < NN) ? counts[idx] : 0;
    lds[tid] = v;
    __syncthreads();
    for (int s = 1; s < 1024; s <<= 1) {
      int tv = (tid >= s) ? lds[tid - s] : 0;
      __syncthreads();
      lds[tid] += tv;
      __syncthreads();
    }
    int incl = lds[tid];
    int c = carry_s;
    __syncthreads();
    if (idx < NN) offs[idx] = c + incl - v;   // exclusive
    if (tid == 1023) carry_s = c + incl;
    __syncthreads();
  }
  if (tid == 0) offs[NN] = carry_s;
}

// eslot[e] = CSR slot of edge e (grouped by rcv)
__global__ __launch_bounds__(256) void k_scatter(
    const int* __restrict__ ei, const int* __restrict__ offs,
    int* __restrict__ cursor, int* __restrict__ eslot) {
  int e = blockIdx.x * 256 + threadIdx.x;
  int r = ei[NEDGE + e];
  int slot = atomicAdd(&cursor[r], 1);
  eslot[e] = offs[r] + slot;
}

// ---------------- per-layer ----------------
// nfup0 = nf0 @ W_up   (only l=0 channel ever needed)
__global__ __launch_bounds__(256) void k_up(
    const float* __restrict__ nf0, const float* __restrict__ Wup,
    float* __restrict__ nfup0) {
  int tid = blockIdx.x * 256 + threadIdx.x;   // N*64
  int n = tid >> 6, k = tid & 63;
  const float* row = nf0 + n * 64;
  float acc = 0.f;
#pragma unroll
  for (int hh = 0; hh < 64; ++hh)
    acc = fmaf(row[hh], Wup[hh * 64 + k], acc);
  nfup0[tid] = acc;
}

// per edge: Y4 (scaled by 1/16) and w = r(len) * nfup0[snd], written to CSR slot
__global__ __launch_bounds__(256) void k_edge(
    const int* __restrict__ ei, const float* __restrict__ shifts,
    const float* __restrict__ pos, const float* __restrict__ nfup0,
    const float* __restrict__ Wr1, const float* __restrict__ br1,
    const float* __restrict__ Wr2, const int* __restrict__ eslot,
    float* __restrict__ w_s, float4* __restrict__ y_s) {
  __shared__ float sW[4096];
  __shared__ float sW1[64];
  __shared__ float sB1[64];
  for (int i = threadIdx.x; i < 4096; i += 256) sW[i] = Wr2[i];
  if (threadIdx.x < 64) { sW1[threadIdx.x] = Wr1[threadIdx.x]; sB1[threadIdx.x] = br1[threadIdx.x]; }
  __syncthreads();
  int e = blockIdx.x * 256 + threadIdx.x;     // exactly E threads
  int s = ei[e], r = ei[NEDGE + e];
  float vx = pos[r * 3 + 0] - pos[s * 3 + 0] + shifts[e * 3 + 0];
  float vy = pos[r * 3 + 1] - pos[s * 3 + 1] + shifts[e * 3 + 1];
  float vz = pos[r * 3 + 2] - pos[s * 3 + 2] + shifts[e * 3 + 2];
  float len = sqrtf(vx * vx + vy * vy + vz * vz);
  float inv = 1.0f / (len + 1e-9f);
  int slot = eslot[e];
  const float c1 = 1.7320508f * 0.0625f;      // sqrt(3)/AVG_NEIGH
  y_s[slot] = make_float4(0.0625f, c1 * vx * inv, c1 * vy * inv, c1 * vz * inv);

  float4 acc[16];
#pragma unroll
  for (int j = 0; j < 16; ++j) acc[j] = make_float4(0.f, 0.f, 0.f, 0.f);
  for (int hh = 0; hh < 64; ++hh) {
    float x = fmaf(len, sW1[hh], sB1[hh]);
    float sl = silu_f(x);
    const float4* W4 = (const float4*)(sW + hh * 64);
#pragma unroll
    for (int j = 0; j < 16; ++j) {
      float4 wq = W4[j];
      acc[j].x = fmaf(sl, wq.x, acc[j].x);
      acc[j].y = fmaf(sl, wq.y, acc[j].y);
      acc[j].z = fmaf(sl, wq.z, acc[j].z);
      acc[j].w = fmaf(sl, wq.w, acc[j].w);
    }
  }
  const float4* nrow = (const float4*)(nfup0 + (size_t)s * 64);
  float4* wrow = (float4*)(w_s + (size_t)slot * 64);
#pragma unroll
  for (int j = 0; j < 16; ++j) {
    float4 nv = nrow[j];
    float4 o;
    o.x = acc[j].x * nv.x; o.y = acc[j].y * nv.y;
    o.z = acc[j].z * nv.z; o.w = acc[j].w * nv.w;
    wrow[j] = o;
  }
}

// wave-per-node CSR gather: agg[n,k,0:4] = sum_e w[e,k]*Y4[e,:]  (Y pre-scaled 1/16)
__global__ __launch_bounds__(256) void k_gather(
    const int* __restrict__ offs, const float* __restrict__ w_s,
    const float4* __restrict__ y_s, float4* __restrict__ agg) {
  int gtid = blockIdx.x * 256 + threadIdx.x;  // N*64
  int n = gtid >> 6;
  int lane = threadIdx.x & 63;
  int beg = offs[n], end = offs[n + 1];
  float a0 = 0.f, a1 = 0.f, a2 = 0.f, a3 = 0.f;
  for (int j = beg; j < end; ++j) {
    float w = w_s[(size_t)j * 64 + lane];
    float4 y = y_s[j];
    a0 = fmaf(w, y.x, a0);
    a1 = fmaf(w, y.y, a1);
    a2 = fmaf(w, y.z, a2);
    a3 = fmaf(w, y.w, a3);
  }
  agg[(size_t)n * 64 + lane] = make_float4(a0, a1, a2, a3);
}

// a = agg@Wmix ; f=1+s+s^2 (s=a[:,:,0]) ; nf = (a*f)@Wprod ; out nf0=nf[...,0], v3=nf[...,1:4]
__global__ __launch_bounds__(256) void k_mix_prod(
    const float4* __restrict__ agg, const float* __restrict__ Wmix,
    const float* __restrict__ Wprod, float* __restrict__ nf0,
    float* __restrict__ v3) {
  __shared__ float sMix[4096];
  __shared__ float sProd[4096];
  __shared__ float4 xb[4][64];
  for (int i = threadIdx.x; i < 4096; i += 256) { sMix[i] = Wmix[i]; sProd[i] = Wprod[i]; }
  int w = threadIdx.x >> 6, lane = threadIdx.x & 63;
  __syncthreads();
  for (int it = 0; it < 4; ++it) {
    int n = it * 2500 + blockIdx.x * 4 + w;   // covers 0..9999 exactly
    xb[w][lane] = agg[(size_t)n * 64 + lane];
    __syncthreads();
    float4 a = make_float4(0.f, 0.f, 0.f, 0.f);
    for (int hh = 0; hh < 64; ++hh) {
      float4 x = xb[w][hh];
      float m = sMix[hh * 64 + lane];
      a.x = fmaf(x.x, m, a.x); a.y = fmaf(x.y, m, a.y);
      a.z = fmaf(x.z, m, a.z); a.w = fmaf(x.w, m, a.w);
    }
    float sv = a.x;
    float f = 1.0f + sv + sv * sv;
    a.x *= f; a.y *= f; a.z *= f; a.w *= f;
    __syncthreads();
    xb[w][lane] = a;
    __syncthreads();
    float4 nf = make_float4(0.f, 0.f, 0.f, 0.f);
    for (int hh = 0; hh < 64; ++hh) {
      float4 x = xb[w][hh];
      float m = sProd[hh * 64 + lane];
      nf.x = fmaf(x.x, m, nf.x); nf.y = fmaf(x.y, m, nf.y);
      nf.z = fmaf(x.z, m, nf.z); nf.w = fmaf(x.w, m, nf.w);
    }
    nf0[(size_t)n * 64 + lane] = nf.x;
    v3[(size_t)n * 192 + lane * 3 + 0] = nf.y;
    v3[(size_t)n * 192 + lane * 3 + 1] = nf.z;
    v3[(size_t)n * 192 + lane * 3 + 2] = nf.w;
    __syncthreads();
  }
}

// q1 = silu(sc@Wro1+bro1) ; gate = silu(sc@Wg) ; pos += sum_h v3*gate*wv
__global__ __launch_bounds__(256) void k_readout(
    const float* __restrict__ nf0, const float* __restrict__ v3,
    const float* __restrict__ Wro1, const float* __restrict__ bro1,
    const float* __restrict__ Wg, const float* __restrict__ wvv,
    float* __restrict__ q1, float* __restrict__ pos) {
  __shared__ float sR[4096];
  __shared__ float sG[4096];
  __shared__ float sx[4][64];
  __shared__ float swv[64];
  for (int i = threadIdx.x; i < 4096; i += 256) { sR[i] = Wro1[i]; sG[i] = Wg[i]; }
  if (threadIdx.x < 64) swv[threadIdx.x] = wvv[threadIdx.x];
  int w = threadIdx.x >> 6, lane = threadIdx.x & 63;
  __syncthreads();
  for (int it = 0; it < 4; ++it) {
    int n = it * 2500 + blockIdx.x * 4 + w;
    sx[w][lane] = nf0[(size_t)n * 64 + lane];
    __syncthreads();
    float q = bro1[lane];
    float g = 0.f;
    for (int hh = 0; hh < 64; ++hh) {
      float x = sx[w][hh];
      q = fmaf(x, sR[hh * 64 + lane], q);
      g = fmaf(x, sG[hh * 64 + lane], g);
    }
    q = silu_f(q);
    g = silu_f(g);
    q1[(size_t)n * 64 + lane] = q;
    float gw = g * swv[lane];
    float p0 = v3[(size_t)n * 192 + lane * 3 + 0] * gw;
    float p1 = v3[(size_t)n * 192 + lane * 3 + 1] * gw;
    float p2 = v3[(size_t)n * 192 + lane * 3 + 2] * gw;
#pragma unroll
    for (int m = 32; m > 0; m >>= 1) {
      p0 += __shfl_xor(p0, m);
      p1 += __shfl_xor(p1, m);
      p2 += __shfl_xor(p2, m);
    }
    if (lane == 0) {
      pos[n * 3 + 0] += p0;
      pos[n * 3 + 1] += p1;
      pos[n * 3 + 2] += p2;
    }
    __syncthreads();
  }
}

// scalars = q1@Wro2 ; h += silu([h,scalars]@Wmlp1+bmlp1)@Wmlp2 + bmlp2
__global__ __launch_bounds__(256) void k_mlp(
    const float* __restrict__ q1, const float* __restrict__ Wro2,
    const float* __restrict__ Wmlp1, const float* __restrict__ bmlp1,
    const float* __restrict__ Wmlp2, const float* __restrict__ bmlp2,
    float* __restrict__ h) {
  __shared__ float sRo2[4096];
  __shared__ float sM1[8192];
  __shared__ float sM2[4096];
  __shared__ float sq[4][64], sh[4][64], ssc[4][64], su[4][64];
  for (int i = threadIdx.x; i < 4096; i += 256) { sRo2[i] = Wro2[i]; sM2[i] = Wmlp2[i]; }
  for (int i = threadIdx.x; i < 8192; i += 256) sM1[i] = Wmlp1[i];
  int w = threadIdx.x >> 6, lane = threadIdx.x & 63;
  __syncthreads();
  for (int it = 0; it < 4; ++it) {
    int n = it * 2500 + blockIdx.x * 4 + w;
    sq[w][lane] = q1[(size_t)n * 64 + lane];
    sh[w][lane] = h[(size_t)n * 64 + lane];
    __syncthreads();
    float sc = 0.f;
    for (int m = 0; m < 64; ++m) sc = fmaf(sq[w][m], sRo2[m * 64 + lane], sc);
    ssc[w][lane] = sc;
    __syncthreads();
    float u = bmlp1[lane];
    for (int j = 0; j < 64; ++j) u = fmaf(sh[w][j], sM1[j * 64 + lane], u);
    for (int j = 0; j < 64; ++j) u = fmaf(ssc[w][j], sM1[(64 + j) * 64 + lane], u);
    u = silu_f(u);
    su[w][lane] = u;
    __syncthreads();
    float ho = sh[w][lane] + bmlp2[lane];
    for (int m = 0; m < 64; ++m) ho = fmaf(su[w][m], sM2[m * 64 + lane], ho);
    h[(size_t)n * 64 + lane] = ho;
    __syncthreads();
  }
}

// ---------------- outputs ----------------
__global__ __launch_bounds__(256) void k_pred(
    const float* __restrict__ h, const float* __restrict__ Wout,
    const float* __restrict__ bout, float* __restrict__ out) {
  __shared__ float sW[704];
  for (int i = threadIdx.x; i < 704; i += 256) sW[i] = Wout[i];
  __syncthreads();
  int n = blockIdx.x * 256 + threadIdx.x;
  if (n >= NN) return;
  float acc[10];
#pragma unroll
  for (int j = 0; j < 10; ++j) acc[j] = bout[j];
  const float* row = h + (size_t)n * 64;
  for (int hh = 0; hh < 64; ++hh) {
    float hv = row[hh];
#pragma unroll
    for (int j = 0; j < 10; ++j) acc[j] = fmaf(hv, sW[hh * 11 + j], acc[j]);
  }
  float* orow = out + (size_t)n * 10;
#pragma unroll
  for (int j = 0; j < 10; ++j) orow[j] = acc[j];
}

__global__ __launch_bounds__(256) void k_batch(
    const int* __restrict__ batch, const float* __restrict__ pos,
    float* __restrict__ bacc) {
  int n = blockIdx.x * 256 + threadIdx.x;
  if (n >= NN) return;
  int b = batch[n];
  atomicAdd(&bacc[b * 4 + 0], pos[n * 3 + 0]);
  atomicAdd(&bacc[b * 4 + 1], pos[n * 3 + 1]);
  atomicAdd(&bacc[b * 4 + 2], pos[n * 3 + 2]);
  atomicAdd(&bacc[b * 4 + 3], 1.0f);
}

__global__ __launch_bounds__(256) void k_predpos(
    const int* __restrict__ batch, const float* __restrict__ pos,
    const float* __restrict__ pos0, const float* __restrict__ bacc,
    float* __restrict__ out) {
  int n = blockIdx.x * 256 + threadIdx.x;
  if (n >= NN) return;
  int b = batch[n];
  float cnt = fmaxf(bacc[b * 4 + 3], 1.0f);
#pragma unroll
  for (int c = 0; c < 3; ++c)
    out[NN * 10 + n * 3 + c] = pos[n * 3 + c] - bacc[b * 4 + c] / cnt - pos0[n * 3 + c];
}

extern "C" void kernel_launch(void* const* d_in, const int* in_sizes, int n_in,
                              void* d_out, int out_size, void* d_ws, size_t ws_size,
                              hipStream_t stream) {
  const float* positions = (const float*)d_in[0];
  const float* node_attrs = (const float*)d_in[1];
  const float* t_in = (const float*)d_in[2];
  const float* shifts = (const float*)d_in[3];
  const int* batch = (const int*)d_in[4];
  const int* edge_index = (const int*)d_in[5];
  const float* W_emb = (const float*)d_in[6];
  const float* b_emb = (const float*)d_in[7];
  const float* W_out = (const float*)d_in[8];
  const float* b_out = (const float*)d_in[9];
  const float* Wr1 = (const float*)d_in[10];
  const float* br1 = (const float*)d_in[11];
  const float* Wr2 = (const float*)d_in[12];
  const float* W_up = (const float*)d_in[13];
  const float* W_mix = (const float*)d_in[14];
  const float* W_prod = (const float*)d_in[15];
  const float* Wro1 = (const float*)d_in[16];
  const float* bro1 = (const float*)d_in[17];
  const float* Wro2 = (const float*)d_in[18];
  const float* Wg = (const float*)d_in[19];
  const float* wv = (const float*)d_in[20];
  const float* Wmlp1 = (const float*)d_in[21];
  const float* bmlp1 = (const float*)d_in[22];
  const float* Wmlp2 = (const float*)d_in[23];
  const float* bmlp2 = (const float*)d_in[24];

  float* ws = (float*)d_ws;
  float* pos_cur = ws + OFF_POS;
  float* hbuf    = ws + OFF_H;
  float* nf0     = ws + OFF_NF0;
  float* nfup0   = ws + OFF_NUP;
  float* v3      = ws + OFF_V3;
  float* q1      = ws + OFF_Q1;
  float4* agg    = (float4*)(ws + OFF_AGG);
  float* w_s     = ws + OFF_WW;
  float4* y_s    = (float4*)(ws + OFF_WY);
  int* eslot     = (int*)(ws + OFF_ESLOT);
  int* csroff    = (int*)(ws + OFF_CSR);
  int* counts    = (int*)(ws + OFF_CNT);
  int* cursor    = (int*)(ws + OFF_CUR);
  float* bacc    = ws + OFF_BACC;

  // zero the accumulators (counts, cursor, bacc are contiguous)
  hipMemsetAsync(counts, 0, (WS_END - OFF_CNT) * sizeof(float), stream);

  k_embed<<<2500, 256, 0, stream>>>(positions, node_attrs, t_in, batch, W_emb, b_emb,
                                    hbuf, nf0, pos_cur);
  k_count<<<625, 256, 0, stream>>>(edge_index, counts);
  k_scan<<<1, 1024, 0, stream>>>(counts, csroff);
  k_scatter<<<625, 256, 0, stream>>>(edge_index, csroff, cursor, eslot);

  for (int i = 0; i < 2; ++i) {
    k_up<<<2500, 256, 0, stream>>>(nf0, W_up + i * 4096, nfup0);
    k_edge<<<625, 256, 0, stream>>>(edge_index, shifts, pos_cur, nfup0,
                                    Wr1 + i * 64, br1 + i * 64, Wr2 + i * 4096,
                                    eslot, w_s, y_s);
    k_gather<<<2500, 256, 0, stream>>>(csroff, w_s, y_s, agg);
    k_mix_prod<<<625, 256, 0, stream>>>(agg, W_mix + i * 4096, W_prod + i * 4096,
                                        nf0, v3);
    k_readout<<<625, 256, 0, stream>>>(nf0, v3, Wro1 + i * 4096, bro1 + i * 64,
                                       Wg + i * 4096, wv + i * 64, q1, pos_cur);
    k_mlp<<<625, 256, 0, stream>>>(q1, Wro2 + i * 4096, Wmlp1 + i * 8192,
                                   bmlp1 + i * 64, Wmlp2 + i * 4096, bmlp2 + i * 64,
                                   hbuf);
  }

  k_pred<<<40, 256, 0, stream>>>(hbuf, W_out, b_out, (float*)d_out);
  k_batch<<<40, 256, 0, stream>>>(batch, pos_cur, bacc);
  k_predpos<<<40, 256, 0, stream>>>(batch, pos_cur, positions, bacc, (float*)d_out);
}

// Round 2
// 431.271 us; speedup vs baseline: 1.1757x; 1.1757x over previous
//
#include <hip/hip_runtime.h>

#define NN 10000
#define NEDGE 160000
#define NBATCH 64

// ---------------- workspace layout (units: floats) ----------------
static constexpr size_t OFF_POS   = 0;                     // N*3
static constexpr size_t OFF_H     = 30016;                 // N*64
static constexpr size_t OFF_NF0   = OFF_H   + 640000;      // N*64
static constexpr size_t OFF_NUP   = OFF_NF0 + 640000;      // N*64
static constexpr size_t OFF_V3    = OFF_NUP + 640000;      // N*192
static constexpr size_t OFF_Q1    = OFF_V3  + 1920000;     // N*64
static constexpr size_t OFF_AGG   = OFF_Q1  + 640000;      // N*256 (float4[N*64])
static constexpr size_t OFF_WW    = OFF_AGG + 2560000;     // E*64
static constexpr size_t OFF_WY    = OFF_WW  + 10240000;    // E*4 (float4[E])
static constexpr size_t OFF_ESLOT = OFF_WY  + 640000;      // E ints
static constexpr size_t OFF_CSR   = OFF_ESLOT + 160000;    // N+1 ints (pad 10016)
static constexpr size_t OFF_CNT   = OFF_CSR + 10016;       // N ints
static constexpr size_t OFF_CUR   = OFF_CNT + 10016;       // N ints
static constexpr size_t OFF_BACC  = OFF_CUR + 10016;       // B*4 floats
static constexpr size_t WS_END    = OFF_BACC + 256;

__device__ __forceinline__ float silu_f(float x) {
  return x / (1.0f + __expf(-x));
}

// ---------------- setup ----------------
// blocks [0,2500): h = [node_attrs/4, t[batch]] @ W_emb + b_emb ; nf0 = h ; pos_cur = positions
// blocks [2500,3125): histogram of rcv into counts
__global__ __launch_bounds__(256) void k_embed_count(
    const float* __restrict__ pos_in, const float* __restrict__ na,
    const float* __restrict__ t, const int* __restrict__ batch,
    const float* __restrict__ Wemb, const float* __restrict__ bemb,
    float* __restrict__ h, float* __restrict__ nf0, float* __restrict__ pos_cur,
    const int* __restrict__ ei, int* __restrict__ counts) {
  if (blockIdx.x >= 2500) {
    int e = (blockIdx.x - 2500) * 256 + threadIdx.x;   // exactly E threads
    atomicAdd(&counts[ei[NEDGE + e]], 1);
    return;
  }
  int tid = blockIdx.x * 256 + threadIdx.x;   // exactly N*64 threads
  int n = tid >> 6, k = tid & 63;
  float acc = bemb[k];
  const float* arow = na + n * 10;
#pragma unroll
  for (int j = 0; j < 10; ++j)
    acc = fmaf(arow[j] * 0.25f, Wemb[j * 64 + k], acc);
  acc = fmaf(t[batch[n]], Wemb[10 * 64 + k], acc);
  h[tid] = acc;
  nf0[tid] = acc;
  if (k < 3) pos_cur[n * 3 + k] = pos_in[n * 3 + k];
}

// single-block exclusive scan: each thread owns 10 contiguous elements,
// one 1024-wide Hillis-Steele scan over partials (~22 barriers total)
__global__ __launch_bounds__(1024) void k_scan(const int* __restrict__ counts,
                                               int* __restrict__ offs) {
  __shared__ int part[1024];
  int tid = threadIdx.x;
  int base = tid * 10;
  int local[10];
  int s = 0;
#pragma unroll
  for (int j = 0; j < 10; ++j) {
    int idx = base + j;
    int v = (idx < NN) ? counts[idx] : 0;
    local[j] = s;              // exclusive prefix within thread
    s += v;
  }
  part[tid] = s;
  __syncthreads();
  for (int d = 1; d < 1024; d <<= 1) {
    int v = (tid >= d) ? part[tid - d] : 0;
    __syncthreads();
    part[tid] += v;
    __syncthreads();
  }
  int excl = (tid == 0) ? 0 : part[tid - 1];
#pragma unroll
  for (int j = 0; j < 10; ++j) {
    int idx = base + j;
    if (idx < NN) offs[idx] = excl + local[j];
  }
  if (tid == 1023) offs[NN] = excl + s;
}

// eslot[e] = CSR slot of edge e (grouped by rcv)
__global__ __launch_bounds__(256) void k_scatter(
    const int* __restrict__ ei, const int* __restrict__ offs,
    int* __restrict__ cursor, int* __restrict__ eslot) {
  int e = blockIdx.x * 256 + threadIdx.x;
  int r = ei[NEDGE + e];
  int slot = atomicAdd(&cursor[r], 1);
  eslot[e] = offs[r] + slot;
}

// ---------------- per-layer ----------------
// nfup0 = nf0 @ W_up (layer 0 only; layer 1's is fused into k_mix_prod)
__global__ __launch_bounds__(256) void k_up(
    const float* __restrict__ nf0, const float* __restrict__ Wup,
    float* __restrict__ nfup0) {
  int tid = blockIdx.x * 256 + threadIdx.x;   // N*64
  int n = tid >> 6, k = tid & 63;
  const float* row = nf0 + n * 64;
  float acc = 0.f;
#pragma unroll
  for (int hh = 0; hh < 64; ++hh)
    acc = fmaf(row[hh], Wup[hh * 64 + k], acc);
  nfup0[tid] = acc;
}

// per edge: Y4 (scaled by 1/16) and w = r(len) * nfup0[snd], written to CSR slot
__global__ __launch_bounds__(256) void k_edge(
    const int* __restrict__ ei, const float* __restrict__ shifts,
    const float* __restrict__ pos, const float* __restrict__ nfup0,
    const float* __restrict__ Wr1, const float* __restrict__ br1,
    const float* __restrict__ Wr2, const int* __restrict__ eslot,
    float* __restrict__ w_s, float4* __restrict__ y_s) {
  __shared__ float sW[4096];
  __shared__ float sW1[64];
  __shared__ float sB1[64];
  for (int i = threadIdx.x; i < 4096; i += 256) sW[i] = Wr2[i];
  if (threadIdx.x < 64) { sW1[threadIdx.x] = Wr1[threadIdx.x]; sB1[threadIdx.x] = br1[threadIdx.x]; }
  __syncthreads();
  int e = blockIdx.x * 256 + threadIdx.x;     // exactly E threads
  int s = ei[e], r = ei[NEDGE + e];
  float vx = pos[r * 3 + 0] - pos[s * 3 + 0] + shifts[e * 3 + 0];
  float vy = pos[r * 3 + 1] - pos[s * 3 + 1] + shifts[e * 3 + 1];
  float vz = pos[r * 3 + 2] - pos[s * 3 + 2] + shifts[e * 3 + 2];
  float len = sqrtf(vx * vx + vy * vy + vz * vz);
  float inv = 1.0f / (len + 1e-9f);
  int slot = eslot[e];
  const float c1 = 1.7320508f * 0.0625f;      // sqrt(3)/AVG_NEIGH
  y_s[slot] = make_float4(0.0625f, c1 * vx * inv, c1 * vy * inv, c1 * vz * inv);

  float4 acc[16];
#pragma unroll
  for (int j = 0; j < 16; ++j) acc[j] = make_float4(0.f, 0.f, 0.f, 0.f);
  for (int hh = 0; hh < 64; ++hh) {
    float x = fmaf(len, sW1[hh], sB1[hh]);
    float sl = silu_f(x);
    const float4* W4 = (const float4*)(sW + hh * 64);
#pragma unroll
    for (int j = 0; j < 16; ++j) {
      float4 wq = W4[j];
      acc[j].x = fmaf(sl, wq.x, acc[j].x);
      acc[j].y = fmaf(sl, wq.y, acc[j].y);
      acc[j].z = fmaf(sl, wq.z, acc[j].z);
      acc[j].w = fmaf(sl, wq.w, acc[j].w);
    }
  }
  const float4* nrow = (const float4*)(nfup0 + (size_t)s * 64);
  float4* wrow = (float4*)(w_s + (size_t)slot * 64);
#pragma unroll
  for (int j = 0; j < 16; ++j) {
    float4 nv = nrow[j];
    float4 o;
    o.x = acc[j].x * nv.x; o.y = acc[j].y * nv.y;
    o.z = acc[j].z * nv.z; o.w = acc[j].w * nv.w;
    wrow[j] = o;
  }
}

// wave-per-node CSR gather: agg[n,k,0:4] = sum_e w[e,k]*Y4[e,:]  (Y pre-scaled 1/16)
__global__ __launch_bounds__(256) void k_gather(
    const int* __restrict__ offs, const float* __restrict__ w_s,
    const float4* __restrict__ y_s, float4* __restrict__ agg) {
  int gtid = blockIdx.x * 256 + threadIdx.x;  // N*64
  int n = gtid >> 6;
  int lane = threadIdx.x & 63;
  int beg = offs[n], end = offs[n + 1];
  float a0 = 0.f, a1 = 0.f, a2 = 0.f, a3 = 0.f;
  for (int j = beg; j < end; ++j) {
    float w = w_s[(size_t)j * 64 + lane];
    float4 y = y_s[j];
    a0 = fmaf(w, y.x, a0);
    a1 = fmaf(w, y.y, a1);
    a2 = fmaf(w, y.z, a2);
    a3 = fmaf(w, y.w, a3);
  }
  agg[(size_t)n * 64 + lane] = make_float4(a0, a1, a2, a3);
}

// a = agg@Wmix ; f=1+s+s^2 ; nf=(a*f)@Wprod ; nf0=nf[...,0], v3=nf[...,1:4]
// optionally (Wup_next != null): nfup0 = nf0_row @ Wup_next (fused next-layer up)
__global__ __launch_bounds__(256) void k_mix_prod(
    const float4* __restrict__ agg, const float* __restrict__ Wmix,
    const float* __restrict__ Wprod, float* __restrict__ nf0,
    float* __restrict__ v3, const float* __restrict__ Wup_next,
    float* __restrict__ nfup0) {
  __shared__ float sMix[4096];
  __shared__ float sProd[4096];
  __shared__ float sUp[4096];
  __shared__ float4 xb[4][64];
  for (int i = threadIdx.x; i < 4096; i += 256) { sMix[i] = Wmix[i]; sProd[i] = Wprod[i]; }
  if (Wup_next)
    for (int i = threadIdx.x; i < 4096; i += 256) sUp[i] = Wup_next[i];
  int w = threadIdx.x >> 6, lane = threadIdx.x & 63;
  __syncthreads();
  for (int it = 0; it < 4; ++it) {
    int n = it * 2500 + blockIdx.x * 4 + w;   // covers 0..9999 exactly
    xb[w][lane] = agg[(size_t)n * 64 + lane];
    __syncthreads();
    float4 a = make_float4(0.f, 0.f, 0.f, 0.f);
    for (int hh = 0; hh < 64; ++hh) {
      float4 x = xb[w][hh];
      float m = sMix[hh * 64 + lane];
      a.x = fmaf(x.x, m, a.x); a.y = fmaf(x.y, m, a.y);
      a.z = fmaf(x.z, m, a.z); a.w = fmaf(x.w, m, a.w);
    }
    float sv = a.x;
    float f = 1.0f + sv + sv * sv;
    a.x *= f; a.y *= f; a.z *= f; a.w *= f;
    __syncthreads();
    xb[w][lane] = a;
    __syncthreads();
    float4 nf = make_float4(0.f, 0.f, 0.f, 0.f);
    for (int hh = 0; hh < 64; ++hh) {
      float4 x = xb[w][hh];
      float m = sProd[hh * 64 + lane];
      nf.x = fmaf(x.x, m, nf.x); nf.y = fmaf(x.y, m, nf.y);
      nf.z = fmaf(x.z, m, nf.z); nf.w = fmaf(x.w, m, nf.w);
    }
    nf0[(size_t)n * 64 + lane] = nf.x;
    v3[(size_t)n * 192 + lane * 3 + 0] = nf.y;
    v3[(size_t)n * 192 + lane * 3 + 1] = nf.z;
    v3[(size_t)n * 192 + lane * 3 + 2] = nf.w;
    if (Wup_next) {
      __syncthreads();
      xb[w][lane] = nf;
      __syncthreads();
      float up = 0.f;
      for (int hh = 0; hh < 64; ++hh)
        up = fmaf(xb[w][hh].x, sUp[hh * 64 + lane], up);
      nfup0[(size_t)n * 64 + lane] = up;
    }
    __syncthreads();
  }
}

// q1 = silu(sc@Wro1+bro1) ; gate = silu(sc@Wg) ; pos += sum_h v3*gate*wv
__global__ __launch_bounds__(256) void k_readout(
    const float* __restrict__ nf0, const float* __restrict__ v3,
    const float* __restrict__ Wro1, const float* __restrict__ bro1,
    const float* __restrict__ Wg, const float* __restrict__ wvv,
    float* __restrict__ q1, float* __restrict__ pos) {
  __shared__ float sR[4096];
  __shared__ float sG[4096];
  __shared__ float sx[4][64];
  __shared__ float swv[64];
  for (int i = threadIdx.x; i < 4096; i += 256) { sR[i] = Wro1[i]; sG[i] = Wg[i]; }
  if (threadIdx.x < 64) swv[threadIdx.x] = wvv[threadIdx.x];
  int w = threadIdx.x >> 6, lane = threadIdx.x & 63;
  __syncthreads();
  for (int it = 0; it < 4; ++it) {
    int n = it * 2500 + blockIdx.x * 4 + w;
    sx[w][lane] = nf0[(size_t)n * 64 + lane];
    __syncthreads();
    float q = bro1[lane];
    float g = 0.f;
    for (int hh = 0; hh < 64; ++hh) {
      float x = sx[w][hh];
      q = fmaf(x, sR[hh * 64 + lane], q);
      g = fmaf(x, sG[hh * 64 + lane], g);
    }
    q = silu_f(q);
    g = silu_f(g);
    q1[(size_t)n * 64 + lane] = q;
    float gw = g * swv[lane];
    float p0 = v3[(size_t)n * 192 + lane * 3 + 0] * gw;
    float p1 = v3[(size_t)n * 192 + lane * 3 + 1] * gw;
    float p2 = v3[(size_t)n * 192 + lane * 3 + 2] * gw;
#pragma unroll
    for (int m = 32; m > 0; m >>= 1) {
      p0 += __shfl_xor(p0, m);
      p1 += __shfl_xor(p1, m);
      p2 += __shfl_xor(p2, m);
    }
    if (lane == 0) {
      pos[n * 3 + 0] += p0;
      pos[n * 3 + 1] += p1;
      pos[n * 3 + 2] += p2;
    }
    __syncthreads();
  }
}

// scalars = q1@Wro2 ; h += silu([h,scalars]@Wmlp1+bmlp1)@Wmlp2 + bmlp2
__global__ __launch_bounds__(256) void k_mlp(
    const float* __restrict__ q1, const float* __restrict__ Wro2,
    const float* __restrict__ Wmlp1, const float* __restrict__ bmlp1,
    const float* __restrict__ Wmlp2, const float* __restrict__ bmlp2,
    float* __restrict__ h) {
  __shared__ float sRo2[4096];
  __shared__ float sM1[8192];
  __shared__ float sM2[4096];
  __shared__ float sq[4][64], sh[4][64], ssc[4][64], su[4][64];
  for (int i = threadIdx.x; i < 4096; i += 256) { sRo2[i] = Wro2[i]; sM2[i] = Wmlp2[i]; }
  for (int i = threadIdx.x; i < 8192; i += 256) sM1[i] = Wmlp1[i];
  int w = threadIdx.x >> 6, lane = threadIdx.x & 63;
  __syncthreads();
  for (int it = 0; it < 4; ++it) {
    int n = it * 2500 + blockIdx.x * 4 + w;
    sq[w][lane] = q1[(size_t)n * 64 + lane];
    sh[w][lane] = h[(size_t)n * 64 + lane];
    __syncthreads();
    float sc = 0.f;
    for (int m = 0; m < 64; ++m) sc = fmaf(sq[w][m], sRo2[m * 64 + lane], sc);
    ssc[w][lane] = sc;
    __syncthreads();
    float u = bmlp1[lane];
    for (int j = 0; j < 64; ++j) u = fmaf(sh[w][j], sM1[j * 64 + lane], u);
    for (int j = 0; j < 64; ++j) u = fmaf(ssc[w][j], sM1[(64 + j) * 64 + lane], u);
    u = silu_f(u);
    su[w][lane] = u;
    __syncthreads();
    float ho = sh[w][lane] + bmlp2[lane];
    for (int m = 0; m < 64; ++m) ho = fmaf(su[w][m], sM2[m * 64 + lane], ho);
    h[(size_t)n * 64 + lane] = ho;
    __syncthreads();
  }
}

// ---------------- outputs ----------------
__global__ __launch_bounds__(256) void k_pred(
    const float* __restrict__ h, const float* __restrict__ Wout,
    const float* __restrict__ bout, float* __restrict__ out) {
  __shared__ float sW[704];
  for (int i = threadIdx.x; i < 704; i += 256) sW[i] = Wout[i];
  __syncthreads();
  int n = blockIdx.x * 256 + threadIdx.x;
  if (n >= NN) return;
  float acc[10];
#pragma unroll
  for (int j = 0; j < 10; ++j) acc[j] = bout[j];
  const float* row = h + (size_t)n * 64;
  for (int hh = 0; hh < 64; ++hh) {
    float hv = row[hh];
#pragma unroll
    for (int j = 0; j < 10; ++j) acc[j] = fmaf(hv, sW[hh * 11 + j], acc[j]);
  }
  float* orow = out + (size_t)n * 10;
#pragma unroll
  for (int j = 0; j < 10; ++j) orow[j] = acc[j];
}

// batch is SORTED: wave-level segmented suffix-reduce, atomics only at run heads
__global__ __launch_bounds__(256) void k_batch(
    const int* __restrict__ batch, const float* __restrict__ pos,
    float* __restrict__ bacc) {
  int n = blockIdx.x * 256 + threadIdx.x;
  int lane = threadIdx.x & 63;
  bool valid = n < NN;
  int b = valid ? batch[n] : -1;
  float p0 = valid ? pos[n * 3 + 0] : 0.f;
  float p1 = valid ? pos[n * 3 + 1] : 0.f;
  float p2 = valid ? pos[n * 3 + 2] : 0.f;
  float c  = valid ? 1.f : 0.f;
#pragma unroll
  for (int d = 1; d < 64; d <<= 1) {
    float q0 = __shfl_down(p0, d);
    float q1 = __shfl_down(p1, d);
    float q2 = __shfl_down(p2, d);
    float qc = __shfl_down(c, d);
    int bd   = __shfl_down(b, d);
    if (lane + d < 64 && bd == b) { p0 += q0; p1 += q1; p2 += q2; c += qc; }
  }
  int bprev = __shfl_up(b, 1);
  bool head = valid && (lane == 0 || bprev != b);
  if (head) {
    atomicAdd(&bacc[b * 4 + 0], p0);
    atomicAdd(&bacc[b * 4 + 1], p1);
    atomicAdd(&bacc[b * 4 + 2], p2);
    atomicAdd(&bacc[b * 4 + 3], c);
  }
}

__global__ __launch_bounds__(256) void k_predpos(
    const int* __restrict__ batch, const float* __restrict__ pos,
    const float* __restrict__ pos0, const float* __restrict__ bacc,
    float* __restrict__ out) {
  int n = blockIdx.x * 256 + threadIdx.x;
  if (n >= NN) return;
  int b = batch[n];
  float cnt = fmaxf(bacc[b * 4 + 3], 1.0f);
#pragma unroll
  for (int c = 0; c < 3; ++c)
    out[NN * 10 + n * 3 + c] = pos[n * 3 + c] - bacc[b * 4 + c] / cnt - pos0[n * 3 + c];
}

extern "C" void kernel_launch(void* const* d_in, const int* in_sizes, int n_in,
                              void* d_out, int out_size, void* d_ws, size_t ws_size,
                              hipStream_t stream) {
  const float* positions = (const float*)d_in[0];
  const float* node_attrs = (const float*)d_in[1];
  const float* t_in = (const float*)d_in[2];
  const float* shifts = (const float*)d_in[3];
  const int* batch = (const int*)d_in[4];
  const int* edge_index = (const int*)d_in[5];
  const float* W_emb = (const float*)d_in[6];
  const float* b_emb = (const float*)d_in[7];
  const float* W_out = (const float*)d_in[8];
  const float* b_out = (const float*)d_in[9];
  const float* Wr1 = (const float*)d_in[10];
  const float* br1 = (const float*)d_in[11];
  const float* Wr2 = (const float*)d_in[12];
  const float* W_up = (const float*)d_in[13];
  const float* W_mix = (const float*)d_in[14];
  const float* W_prod = (const float*)d_in[15];
  const float* Wro1 = (const float*)d_in[16];
  const float* bro1 = (const float*)d_in[17];
  const float* Wro2 = (const float*)d_in[18];
  const float* Wg = (const float*)d_in[19];
  const float* wv = (const float*)d_in[20];
  const float* Wmlp1 = (const float*)d_in[21];
  const float* bmlp1 = (const float*)d_in[22];
  const float* Wmlp2 = (const float*)d_in[23];
  const float* bmlp2 = (const float*)d_in[24];

  float* ws = (float*)d_ws;
  float* pos_cur = ws + OFF_POS;
  float* hbuf    = ws + OFF_H;
  float* nf0     = ws + OFF_NF0;
  float* nfup0   = ws + OFF_NUP;
  float* v3      = ws + OFF_V3;
  float* q1      = ws + OFF_Q1;
  float4* agg    = (float4*)(ws + OFF_AGG);
  float* w_s     = ws + OFF_WW;
  float4* y_s    = (float4*)(ws + OFF_WY);
  int* eslot     = (int*)(ws + OFF_ESLOT);
  int* csroff    = (int*)(ws + OFF_CSR);
  int* counts    = (int*)(ws + OFF_CNT);
  int* cursor    = (int*)(ws + OFF_CUR);
  float* bacc    = ws + OFF_BACC;

  // zero the accumulators (counts, cursor, bacc are contiguous)
  hipMemsetAsync(counts, 0, (WS_END - OFF_CNT) * sizeof(float), stream);

  k_embed_count<<<3125, 256, 0, stream>>>(positions, node_attrs, t_in, batch,
                                          W_emb, b_emb, hbuf, nf0, pos_cur,
                                          edge_index, counts);
  k_scan<<<1, 1024, 0, stream>>>(counts, csroff);
  k_scatter<<<625, 256, 0, stream>>>(edge_index, csroff, cursor, eslot);

  k_up<<<2500, 256, 0, stream>>>(nf0, W_up, nfup0);
  for (int i = 0; i < 2; ++i) {
    k_edge<<<625, 256, 0, stream>>>(edge_index, shifts, pos_cur, nfup0,
                                    Wr1 + i * 64, br1 + i * 64, Wr2 + i * 4096,
                                    eslot, w_s, y_s);
    k_gather<<<2500, 256, 0, stream>>>(csroff, w_s, y_s, agg);
    k_mix_prod<<<625, 256, 0, stream>>>(agg, W_mix + i * 4096, W_prod + i * 4096,
                                        nf0, v3,
                                        (i == 0) ? (W_up + 4096) : nullptr, nfup0);
    k_readout<<<625, 256, 0, stream>>>(nf0, v3, Wro1 + i * 4096, bro1 + i * 64,
                                       Wg + i * 4096, wv + i * 64, q1, pos_cur);
    k_mlp<<<625, 256, 0, stream>>>(q1, Wro2 + i * 4096, Wmlp1 + i * 8192,
                                   bmlp1 + i * 64, Wmlp2 + i * 4096, bmlp2 + i * 64,
                                   hbuf);
  }

  k_pred<<<40, 256, 0, stream>>>(hbuf, W_out, b_out, (float*)d_out);
  k_batch<<<40, 256, 0, stream>>>(batch, pos_cur, bacc);
  k_predpos<<<40, 256, 0, stream>>>(batch, pos_cur, positions, bacc, (float*)d_out);
}

// Round 4
// 400.728 us; speedup vs baseline: 1.2653x; 1.0762x over previous
//
#include <hip/hip_runtime.h>

#define NN 10000
#define NEDGE 160000
#define NBATCH 64

// ---------------- workspace layout (units: floats) ----------------
static constexpr size_t OFF_POS   = 0;                     // N*3
static constexpr size_t OFF_H     = 30016;                 // N*64
static constexpr size_t OFF_NF0   = OFF_H   + 640000;      // N*64
static constexpr size_t OFF_NUP   = OFF_NF0 + 640000;      // N*64
static constexpr size_t OFF_V3    = OFF_NUP + 640000;      // N*192
static constexpr size_t OFF_Q1    = OFF_V3  + 1920000;     // (unused)
static constexpr size_t OFF_AGG   = OFF_Q1  + 640000;      // N*256 (float4[N*64])
static constexpr size_t OFF_WW    = OFF_AGG + 2560000;     // E*64
static constexpr size_t OFF_WY    = OFF_WW  + 10240000;    // E*4 (float4[E])
static constexpr size_t OFF_ESLOT = OFF_WY  + 640000;      // E ints
static constexpr size_t OFF_CSR   = OFF_ESLOT + 160000;    // N+1 ints (pad 10016)
static constexpr size_t OFF_CNT   = OFF_CSR + 10016;       // N ints
static constexpr size_t OFF_CUR   = OFF_CNT + 10016;       // N ints
static constexpr size_t OFF_BACC  = OFF_CUR + 10016;       // B*4 floats
static constexpr size_t WS_END    = OFF_BACC + 256;

__device__ __forceinline__ float silu_f(float x) {
  return x / (1.0f + __expf(-x));
}

// ---------------- setup ----------------
// blocks [0,2500): h = [na/4, t[batch]]@W_emb + b_emb ; nf0 = h ; pos_cur = positions
//                  then fused: nfup0 = h @ Wup0 (row exchanged via LDS)
// blocks [2500,3125): histogram of rcv into counts
__global__ __launch_bounds__(256) void k_embed_count_up(
    const float* __restrict__ pos_in, const float* __restrict__ na,
    const float* __restrict__ t, const int* __restrict__ batch,
    const float* __restrict__ Wemb, const float* __restrict__ bemb,
    const float* __restrict__ Wup0,
    float* __restrict__ h, float* __restrict__ nf0, float* __restrict__ pos_cur,
    float* __restrict__ nfup0,
    const int* __restrict__ ei, int* __restrict__ counts) {
  if (blockIdx.x >= 2500) {
    int e = (blockIdx.x - 2500) * 256 + threadIdx.x;   // exactly E threads
    atomicAdd(&counts[ei[NEDGE + e]], 1);
    return;
  }
  __shared__ float sx[4][64];
  int tid = blockIdx.x * 256 + threadIdx.x;   // exactly N*64 threads
  int n = tid >> 6, k = tid & 63;
  int w = threadIdx.x >> 6;
  float acc = bemb[k];
  const float* arow = na + n * 10;
#pragma unroll
  for (int j = 0; j < 10; ++j)
    acc = fmaf(arow[j] * 0.25f, Wemb[j * 64 + k], acc);
  acc = fmaf(t[batch[n]], Wemb[10 * 64 + k], acc);
  h[tid] = acc;
  nf0[tid] = acc;
  if (k < 3) pos_cur[n * 3 + k] = pos_in[n * 3 + k];
  sx[w][k] = acc;
  __syncthreads();
  float up = 0.f;
  for (int hh = 0; hh < 64; ++hh)
    up = fmaf(sx[w][hh], Wup0[hh * 64 + k], up);
  nfup0[tid] = up;
}

// single-block exclusive scan: thread owns 10 elems, one 1024-wide scan of partials
__global__ __launch_bounds__(1024) void k_scan(const int* __restrict__ counts,
                                               int* __restrict__ offs) {
  __shared__ int part[1024];
  int tid = threadIdx.x;
  int base = tid * 10;
  int local[10];
  int s = 0;
#pragma unroll
  for (int j = 0; j < 10; ++j) {
    int idx = base + j;
    int v = (idx < NN) ? counts[idx] : 0;
    local[j] = s;
    s += v;
  }
  part[tid] = s;
  __syncthreads();
  for (int d = 1; d < 1024; d <<= 1) {
    int v = (tid >= d) ? part[tid - d] : 0;
    __syncthreads();
    part[tid] += v;
    __syncthreads();
  }
  int excl = (tid == 0) ? 0 : part[tid - 1];
#pragma unroll
  for (int j = 0; j < 10; ++j) {
    int idx = base + j;
    if (idx < NN) offs[idx] = excl + local[j];
  }
  if (tid == 1023) offs[NN] = excl + s;
}

// eslot[e] = CSR slot of edge e (grouped by rcv)
__global__ __launch_bounds__(256) void k_scatter(
    const int* __restrict__ ei, const int* __restrict__ offs,
    int* __restrict__ cursor, int* __restrict__ eslot) {
  int e = blockIdx.x * 256 + threadIdx.x;
  int r = ei[NEDGE + e];
  int slot = atomicAdd(&cursor[r], 1);
  eslot[e] = offs[r] + slot;
}

// ---------------- per-layer ----------------
// per edge: Y4 (scaled 1/16) and w = r(len) * nfup0[snd] into CSR slot.
// Weights read DIRECTLY from global with wave-uniform indices -> scalar s_load
// path (constant cache), freeing the LDS pipe (was the 54us bottleneck).
__global__ __launch_bounds__(256) void k_edge(
    const int* __restrict__ ei, const float* __restrict__ shifts,
    const float* __restrict__ pos, const float* __restrict__ nfup0,
    const float* __restrict__ Wr1, const float* __restrict__ br1,
    const float* __restrict__ Wr2, const int* __restrict__ eslot,
    float* __restrict__ w_s, float4* __restrict__ y_s) {
  int e = blockIdx.x * 256 + threadIdx.x;     // exactly E threads
  int s = ei[e], r = ei[NEDGE + e];
  float vx = pos[r * 3 + 0] - pos[s * 3 + 0] + shifts[e * 3 + 0];
  float vy = pos[r * 3 + 1] - pos[s * 3 + 1] + shifts[e * 3 + 1];
  float vz = pos[r * 3 + 2] - pos[s * 3 + 2] + shifts[e * 3 + 2];
  float len = sqrtf(vx * vx + vy * vy + vz * vz);
  float inv = 1.0f / (len + 1e-9f);
  int slot = eslot[e];
  const float c1 = 1.7320508f * 0.0625f;      // sqrt(3)/AVG_NEIGH
  y_s[slot] = make_float4(0.0625f, c1 * vx * inv, c1 * vy * inv, c1 * vz * inv);

  const float4* W2q = (const float4*)Wr2;     // [64][16] float4, uniform reads
  float4 acc[16];
#pragma unroll
  for (int j = 0; j < 16; ++j) acc[j] = make_float4(0.f, 0.f, 0.f, 0.f);
  for (int hh = 0; hh < 64; ++hh) {
    float x = fmaf(len, Wr1[hh], br1[hh]);    // uniform -> s_load
    float sl = silu_f(x);
#pragma unroll
    for (int j = 0; j < 16; ++j) {
      float4 wq = W2q[hh * 16 + j];           // uniform -> s_load_dwordx4
      acc[j].x = fmaf(sl, wq.x, acc[j].x);
      acc[j].y = fmaf(sl, wq.y, acc[j].y);
      acc[j].z = fmaf(sl, wq.z, acc[j].z);
      acc[j].w = fmaf(sl, wq.w, acc[j].w);
    }
  }
  const float4* nrow = (const float4*)(nfup0 + (size_t)s * 64);
  float4* wrow = (float4*)(w_s + (size_t)slot * 64);
#pragma unroll
  for (int j = 0; j < 16; ++j) {
    float4 nv = nrow[j];
    float4 o;
    o.x = acc[j].x * nv.x; o.y = acc[j].y * nv.y;
    o.z = acc[j].z * nv.z; o.w = acc[j].w * nv.w;
    wrow[j] = o;
  }
}

// wave-per-node CSR gather: agg[n,k,0:4] = sum_e w[e,k]*Y4[e,:]
__global__ __launch_bounds__(256) void k_gather(
    const int* __restrict__ offs, const float* __restrict__ w_s,
    const float4* __restrict__ y_s, float4* __restrict__ agg) {
  int gtid = blockIdx.x * 256 + threadIdx.x;  // N*64 threads, wave per node
  int n = gtid >> 6;
  int lane = threadIdx.x & 63;
  int beg = offs[n], end = offs[n + 1];
  float a0 = 0.f, a1 = 0.f, a2 = 0.f, a3 = 0.f;
  for (int j = beg; j < end; ++j) {
    float w = w_s[(size_t)j * 64 + lane];
    float4 y = y_s[j];
    a0 = fmaf(w, y.x, a0);
    a1 = fmaf(w, y.y, a1);
    a2 = fmaf(w, y.z, a2);
    a3 = fmaf(w, y.w, a3);
  }
  agg[(size_t)n * 64 + lane] = make_float4(a0, a1, a2, a3);
}

// a = agg@Wmix ; f=1+s+s^2 ; nf=(a*f)@Wprod ; nf0=nf[...,0], v3=nf[...,1:4]
// optionally: nfup0 = nf0_row @ Wup_next (fused next-layer up).  512 thr, 56KB LDS.
__global__ __launch_bounds__(512) void k_mix_prod(
    const float4* __restrict__ agg, const float* __restrict__ Wmix,
    const float* __restrict__ Wprod, float* __restrict__ nf0,
    float* __restrict__ v3, const float* __restrict__ Wup_next,
    float* __restrict__ nfup0) {
  __shared__ float sMix[4096];
  __shared__ float sProd[4096];
  __shared__ float sUp[4096];
  __shared__ float4 xb[8][64];
  for (int i = threadIdx.x; i < 4096; i += 512) { sMix[i] = Wmix[i]; sProd[i] = Wprod[i]; }
  if (Wup_next)
    for (int i = threadIdx.x; i < 4096; i += 512) sUp[i] = Wup_next[i];
  int w = threadIdx.x >> 6, lane = threadIdx.x & 63;
  __syncthreads();
  for (int it = 0; it < 5; ++it) {
    int n = it * 2000 + blockIdx.x * 8 + w;   // grid 250: covers 0..9999 exactly
    xb[w][lane] = agg[(size_t)n * 64 + lane];
    __syncthreads();
    float4 a = make_float4(0.f, 0.f, 0.f, 0.f);
    for (int hh = 0; hh < 64; ++hh) {
      float4 x = xb[w][hh];
      float m = sMix[hh * 64 + lane];
      a.x = fmaf(x.x, m, a.x); a.y = fmaf(x.y, m, a.y);
      a.z = fmaf(x.z, m, a.z); a.w = fmaf(x.w, m, a.w);
    }
    float sv = a.x;
    float f = 1.0f + sv + sv * sv;
    a.x *= f; a.y *= f; a.z *= f; a.w *= f;
    __syncthreads();
    xb[w][lane] = a;
    __syncthreads();
    float4 nf = make_float4(0.f, 0.f, 0.f, 0.f);
    for (int hh = 0; hh < 64; ++hh) {
      float4 x = xb[w][hh];
      float m = sProd[hh * 64 + lane];
      nf.x = fmaf(x.x, m, nf.x); nf.y = fmaf(x.y, m, nf.y);
      nf.z = fmaf(x.z, m, nf.z); nf.w = fmaf(x.w, m, nf.w);
    }
    nf0[(size_t)n * 64 + lane] = nf.x;
    v3[(size_t)n * 192 + lane * 3 + 0] = nf.y;
    v3[(size_t)n * 192 + lane * 3 + 1] = nf.z;
    v3[(size_t)n * 192 + lane * 3 + 2] = nf.w;
    if (Wup_next) {
      __syncthreads();
      xb[w][lane].x = nf.x;
      __syncthreads();
      float up = 0.f;
      for (int hh = 0; hh < 64; ++hh)
        up = fmaf(xb[w][hh].x, sUp[hh * 64 + lane], up);
      nfup0[(size_t)n * 64 + lane] = up;
    }
    __syncthreads();
  }
}

// fused readout + MLP: q=silu(sc@Wro1+b) ; gate=silu(sc@Wg) ; pos += sum v3*gate*wv ;
// scalars=q@Wro2 ; h += silu([h,scalars]@Wmlp1+b)@Wmlp2 + b2.   512 thr, ~107KB LDS.
__global__ __launch_bounds__(512) void k_readout_mlp(
    const float* __restrict__ nf0, const float* __restrict__ v3,
    const float* __restrict__ Wro1, const float* __restrict__ bro1,
    const float* __restrict__ Wg, const float* __restrict__ wvv,
    const float* __restrict__ Wro2,
    const float* __restrict__ Wmlp1, const float* __restrict__ bmlp1,
    const float* __restrict__ Wmlp2, const float* __restrict__ bmlp2,
    float* __restrict__ pos, float* __restrict__ h) {
  __shared__ float sR[4096];
  __shared__ float sG[4096];
  __shared__ float sRo2[4096];
  __shared__ float sM1[8192];
  __shared__ float sM2[4096];
  __shared__ float sx[8][64], sq[8][64], ssc[8][64], sh[8][64], su[8][64];
  __shared__ float swv[64];
  for (int i = threadIdx.x; i < 4096; i += 512) {
    sR[i] = Wro1[i]; sG[i] = Wg[i]; sRo2[i] = Wro2[i]; sM2[i] = Wmlp2[i];
  }
  for (int i = threadIdx.x; i < 8192; i += 512) sM1[i] = Wmlp1[i];
  if (threadIdx.x < 64) swv[threadIdx.x] = wvv[threadIdx.x];
  int w = threadIdx.x >> 6, lane = threadIdx.x & 63;
  __syncthreads();
  for (int it = 0; it < 5; ++it) {
    int n = it * 2000 + blockIdx.x * 8 + w;
    sx[w][lane] = nf0[(size_t)n * 64 + lane];
    sh[w][lane] = h[(size_t)n * 64 + lane];
    __syncthreads();
    float q = bro1[lane];
    float g = 0.f;
    for (int hh = 0; hh < 64; ++hh) {
      float x = sx[w][hh];
      q = fmaf(x, sR[hh * 64 + lane], q);
      g = fmaf(x, sG[hh * 64 + lane], g);
    }
    q = silu_f(q);
    g = silu_f(g);
    float gw = g * swv[lane];
    float p0 = v3[(size_t)n * 192 + lane * 3 + 0] * gw;
    float p1 = v3[(size_t)n * 192 + lane * 3 + 1] * gw;
    float p2 = v3[(size_t)n * 192 + lane * 3 + 2] * gw;
#pragma unroll
    for (int m = 32; m > 0; m >>= 1) {
      p0 += __shfl_xor(p0, m);
      p1 += __shfl_xor(p1, m);
      p2 += __shfl_xor(p2, m);
    }
    if (lane == 0) {
      pos[n * 3 + 0] += p0;
      pos[n * 3 + 1] += p1;
      pos[n * 3 + 2] += p2;
    }
    sq[w][lane] = q;
    __syncthreads();
    float sc = 0.f;
    for (int m = 0; m < 64; ++m) sc = fmaf(sq[w][m], sRo2[m * 64 + lane], sc);
    ssc[w][lane] = sc;
    __syncthreads();
    float u = bmlp1[lane];
    for (int j = 0; j < 64; ++j) u = fmaf(sh[w][j], sM1[j * 64 + lane], u);
    for (int j = 0; j < 64; ++j) u = fmaf(ssc[w][j], sM1[(64 + j) * 64 + lane], u);
    u = silu_f(u);
    su[w][lane] = u;
    __syncthreads();
    float ho = sh[w][lane] + bmlp2[lane];
    for (int m = 0; m < 64; ++m) ho = fmaf(su[w][m], sM2[m * 64 + lane], ho);
    h[(size_t)n * 64 + lane] = ho;
    __syncthreads();
  }
}

// ---------------- outputs ----------------
__global__ __launch_bounds__(256) void k_pred(
    const float* __restrict__ h, const float* __restrict__ Wout,
    const float* __restrict__ bout, float* __restrict__ out) {
  __shared__ float sW[704];
  for (int i = threadIdx.x; i < 704; i += 256) sW[i] = Wout[i];
  __syncthreads();
  int n = blockIdx.x * 256 + threadIdx.x;
  if (n >= NN) return;
  float acc[10];
#pragma unroll
  for (int j = 0; j < 10; ++j) acc[j] = bout[j];
  const float* row = h + (size_t)n * 64;
  for (int hh = 0; hh < 64; ++hh) {
    float hv = row[hh];
#pragma unroll
    for (int j = 0; j < 10; ++j) acc[j] = fmaf(hv, sW[hh * 11 + j], acc[j]);
  }
  float* orow = out + (size_t)n * 10;
#pragma unroll
  for (int j = 0; j < 10; ++j) orow[j] = acc[j];
}

// batch is SORTED: wave-level segmented reduce, atomics only at run heads
__global__ __launch_bounds__(256) void k_batch(
    const int* __restrict__ batch, const float* __restrict__ pos,
    float* __restrict__ bacc) {
  int n = blockIdx.x * 256 + threadIdx.x;
  int lane = threadIdx.x & 63;
  bool valid = n < NN;
  int b = valid ? batch[n] : -1;
  float p0 = valid ? pos[n * 3 + 0] : 0.f;
  float p1 = valid ? pos[n * 3 + 1] : 0.f;
  float p2 = valid ? pos[n * 3 + 2] : 0.f;
  float c  = valid ? 1.f : 0.f;
#pragma unroll
  for (int d = 1; d < 64; d <<= 1) {
    float q0 = __shfl_down(p0, d);
    float q1 = __shfl_down(p1, d);
    float q2 = __shfl_down(p2, d);
    float qc = __shfl_down(c, d);
    int bd   = __shfl_down(b, d);
    if (lane + d < 64 && bd == b) { p0 += q0; p1 += q1; p2 += q2; c += qc; }
  }
  int bprev = __shfl_up(b, 1);
  bool head = valid && (lane == 0 || bprev != b);
  if (head) {
    atomicAdd(&bacc[b * 4 + 0], p0);
    atomicAdd(&bacc[b * 4 + 1], p1);
    atomicAdd(&bacc[b * 4 + 2], p2);
    atomicAdd(&bacc[b * 4 + 3], c);
  }
}

__global__ __launch_bounds__(256) void k_predpos(
    const int* __restrict__ batch, const float* __restrict__ pos,
    const float* __restrict__ pos0, const float* __restrict__ bacc,
    float* __restrict__ out) {
  int n = blockIdx.x * 256 + threadIdx.x;
  if (n >= NN) return;
  int b = batch[n];
  float cnt = fmaxf(bacc[b * 4 + 3], 1.0f);
#pragma unroll
  for (int c = 0; c < 3; ++c)
    out[NN * 10 + n * 3 + c] = pos[n * 3 + c] - bacc[b * 4 + c] / cnt - pos0[n * 3 + c];
}

extern "C" void kernel_launch(void* const* d_in, const int* in_sizes, int n_in,
                              void* d_out, int out_size, void* d_ws, size_t ws_size,
                              hipStream_t stream) {
  const float* positions = (const float*)d_in[0];
  const float* node_attrs = (const float*)d_in[1];
  const float* t_in = (const float*)d_in[2];
  const float* shifts = (const float*)d_in[3];
  const int* batch = (const int*)d_in[4];
  const int* edge_index = (const int*)d_in[5];
  const float* W_emb = (const float*)d_in[6];
  const float* b_emb = (const float*)d_in[7];
  const float* W_out = (const float*)d_in[8];
  const float* b_out = (const float*)d_in[9];
  const float* Wr1 = (const float*)d_in[10];
  const float* br1 = (const float*)d_in[11];
  const float* Wr2 = (const float*)d_in[12];
  const float* W_up = (const float*)d_in[13];
  const float* W_mix = (const float*)d_in[14];
  const float* W_prod = (const float*)d_in[15];
  const float* Wro1 = (const float*)d_in[16];
  const float* bro1 = (const float*)d_in[17];
  const float* Wro2 = (const float*)d_in[18];
  const float* Wg = (const float*)d_in[19];
  const float* wv = (const float*)d_in[20];
  const float* Wmlp1 = (const float*)d_in[21];
  const float* bmlp1 = (const float*)d_in[22];
  const float* Wmlp2 = (const float*)d_in[23];
  const float* bmlp2 = (const float*)d_in[24];

  float* ws = (float*)d_ws;
  float* pos_cur = ws + OFF_POS;
  float* hbuf    = ws + OFF_H;
  float* nf0     = ws + OFF_NF0;
  float* nfup0   = ws + OFF_NUP;
  float* v3      = ws + OFF_V3;
  float4* agg    = (float4*)(ws + OFF_AGG);
  float* w_s     = ws + OFF_WW;
  float4* y_s    = (float4*)(ws + OFF_WY);
  int* eslot     = (int*)(ws + OFF_ESLOT);
  int* csroff    = (int*)(ws + OFF_CSR);
  int* counts    = (int*)(ws + OFF_CNT);
  int* cursor    = (int*)(ws + OFF_CUR);
  float* bacc    = ws + OFF_BACC;

  hipMemsetAsync(counts, 0, (WS_END - OFF_CNT) * sizeof(float), stream);

  k_embed_count_up<<<3125, 256, 0, stream>>>(positions, node_attrs, t_in, batch,
                                             W_emb, b_emb, W_up,
                                             hbuf, nf0, pos_cur, nfup0,
                                             edge_index, counts);
  k_scan<<<1, 1024, 0, stream>>>(counts, csroff);
  k_scatter<<<625, 256, 0, stream>>>(edge_index, csroff, cursor, eslot);

  for (int i = 0; i < 2; ++i) {
    k_edge<<<625, 256, 0, stream>>>(edge_index, shifts, pos_cur, nfup0,
                                    Wr1 + i * 64, br1 + i * 64, Wr2 + i * 4096,
                                    eslot, w_s, y_s);
    k_gather<<<2500, 256, 0, stream>>>(csroff, w_s, y_s, agg);
    k_mix_prod<<<250, 512, 0, stream>>>(agg, W_mix + i * 4096, W_prod + i * 4096,
                                        nf0, v3,
                                        (i == 0) ? (W_up + 4096) : nullptr, nfup0);
    k_readout_mlp<<<250, 512, 0, stream>>>(nf0, v3, Wro1 + i * 4096, bro1 + i * 64,
                                           Wg + i * 4096, wv + i * 64,
                                           Wro2 + i * 4096,
                                           Wmlp1 + i * 8192, bmlp1 + i * 64,
                                           Wmlp2 + i * 4096, bmlp2 + i * 64,
                                           pos_cur, hbuf);
  }

  k_pred<<<40, 256, 0, stream>>>(hbuf, W_out, b_out, (float*)d_out);
  k_batch<<<40, 256, 0, stream>>>(batch, pos_cur, bacc);
  k_predpos<<<40, 256, 0, stream>>>(batch, pos_cur, positions, bacc, (float*)d_out);
}